// Round 4
// baseline (739.161 us; speedup 1.0000x reference)
//
#include <hip/hip_runtime.h>
#include <math.h>

#define BB 16
#define SS 4096
#define HH 1024
#define SCH 64    // s-chunk for fallback weighted-sum kernel

// d_ws layout (fused path, needs ~6.27 MB):
//   [0, 4 MB)                 : W tiled hi/lo bf16, [ct(8)][kc(32)] blocks of 16 KB
//   [4 MB, +256 KB)           : scores, B*S fp32 (atomicAdd target)
//   [4 MB+256 KB, +2 KB)      : arrival counters, 512 ints (one per (b,row-tile))
//   [4 MB+258 KB, +4 KB)      : (m_t, z_t) per tile, 512 pairs f32
//   [4 MB+272 KB, +2 MB)      : v_t[h] per tile: [512][1024] f32
// Fallback path (ws < NEED): round-3 layout (part aliases Bbuf after gemm).
//
// LDS fragment layout (A and B identical): row r (0..127) occupies 64 B,
// split into 4 slots of 16 B. Element k (0..31) lives at
//   byte = r*64 + (SWZ(r, k>>3))*16 + (k&7)*2,  SWZ(r,s) = s ^ ((r>>1)&3)

typedef __attribute__((ext_vector_type(8))) short bf16x8;
typedef __attribute__((ext_vector_type(16))) float f32x16;

__device__ __forceinline__ void gl_lds16(const void* g, void* l) {
  __builtin_amdgcn_global_load_lds(
      (const __attribute__((address_space(1))) void*)g,
      (__attribute__((address_space(3))) void*)l, 16, 0, 0);
}

// ---- W -> tiled hi/lo bf16 (truncation split), swizzled slot layout --------
__global__ __launch_bounds__(256) void conv_w(const float* __restrict__ W,
                                              unsigned short* __restrict__ Bbuf) {
  int ct = blockIdx.x, kc = blockIdx.y;
  unsigned short* blk = Bbuf + (size_t)(ct * 32 + kc) * 8192;  // 16 KB / 2
  int tid = threadIdx.x;
#pragma unroll
  for (int it = 0; it < 16; ++it) {
    int flat = it * 256 + tid;
    int n = flat >> 5, kk = flat & 31;
    float f = W[(size_t)(ct * 128 + n) * HH + kc * 32 + kk];
    unsigned u = __float_as_uint(f);
    float hf = __uint_as_float(u & 0xffff0000u);
    int slot = (kk >> 3) ^ ((n >> 1) & 3);
    int idx = n * 32 + slot * 8 + (kk & 7);
    blk[idx] = (unsigned short)(u >> 16);
    blk[4096 + idx] = (unsigned short)(__float_as_uint(f - hf) >> 16);
  }
}

// ---- scores GEMM + fused flash-style softmax/weighted-sum epilogue ---------
// grid (8, 512) flat-swizzled so all 8 col-tiles of a row-tile land on ONE XCD.
// Double-buffered LDS (64 KB): A0|B0|A1|B1, one barrier per K-step.
// Fused epilogue: the 8 ct-blocks of a row-tile arrive on a device-scope
// counter; the LAST one re-reads the completed 128 scores (atomic reads ->
// coherent regardless of actual block->XCD mapping), computes per-tile
// m_t / z_t / v_t[h] = sum_r exp(sc_r - m_t) * x[r,h] (x tile is L2-hot),
// and stores them for a tiny per-b combine kernel.
__global__ __launch_bounds__(256, 2) void scores_gemm(
    const float* __restrict__ x, const int* __restrict__ lengths,
    const unsigned short* __restrict__ Bbuf, const float* __restrict__ bias,
    const float* __restrict__ key, float* __restrict__ scores,
    int* __restrict__ cnt, float* __restrict__ mzb, float* __restrict__ vb,
    int fused) {
  // ---- XCD-aware bijective swizzle ----
  int f = blockIdx.y * 8 + blockIdx.x;
  int r8 = f & 7, j = f >> 3;
  int t = r8 + (j & ~7);
  int ct = j & 7;
  int b = t >> 5;
  int s0 = (t & 31) * 128;
  if (s0 >= lengths[b]) return;

  __shared__ char lds[65536];
  char* A0 = lds;              // 16 KB (hi 8 + lo 8)
  char* B0 = lds + 16384;      // 16 KB
  char* A1 = lds + 32768;
  char* B1 = lds + 49152;

  int tid = threadIdx.x;
  int lane = tid & 63, w = tid >> 6;
  int wm = w & 1, wn = w >> 1;

  f32x16 acc[2][2];
#pragma unroll
  for (int mt = 0; mt < 2; ++mt)
#pragma unroll
    for (int nt = 0; nt < 2; ++nt)
#pragma unroll
      for (int i = 0; i < 16; ++i) acc[mt][nt][i] = 0.f;

  const float* xb = x + ((size_t)b * SS + s0) * HH;
  const char* Bblk0 = (const char*)Bbuf + (size_t)ct * 32 * 16384;

  int ar = tid >> 3;            // staging row 0..31 (+32*it)
  int ak8 = tid & 7;            // k-octet index (4 elements)
  int awoff = (((ak8 >> 1) ^ ((ar >> 1) & 3)) << 4) + ((ak8 & 1) << 3);

  int mrow = lane & 31;         // MFMA m (and n) index
  int khsel = lane >> 5;        // which 8-k half of a 16-k fragment
  int rx = (mrow >> 1) & 3;
  int soff0 = ((khsel ^ rx)) << 4;        // kh=0 slot byte offset
  int soff1 = (((2 + khsel) ^ rx)) << 4;  // kh=1 slot byte offset
  int rbA = (wm * 64 + mrow) * 64;
  int rbB = (wn * 64 + mrow) * 64;

  float4 v[4];

#define STAGE_ISSUE(KC, BDST)                                              \
  {                                                                        \
    const char* Bblk = Bblk0 + (KC) * 16384;                               \
    _Pragma("unroll") for (int i = 0; i < 4; ++i) {                        \
      int c = w * 4 + i;                                                   \
      gl_lds16(Bblk + c * 1024 + lane * 16, (BDST) + c * 1024);            \
    }                                                                      \
    _Pragma("unroll") for (int it = 0; it < 4; ++it)                       \
      v[it] = *(const float4*)(xb + (size_t)(ar + it * 32) * HH +          \
                               (KC) * 32 + ak8 * 4);                       \
  }

#define A_WRITE(ADST)                                                      \
  {                                                                        \
    _Pragma("unroll") for (int it = 0; it < 4; ++it) {                     \
      int rr = ar + it * 32;                                               \
      unsigned u0 = __float_as_uint(v[it].x), u1 = __float_as_uint(v[it].y);\
      unsigned u2 = __float_as_uint(v[it].z), u3 = __float_as_uint(v[it].w);\
      float l0 = v[it].x - __uint_as_float(u0 & 0xffff0000u);              \
      float l1 = v[it].y - __uint_as_float(u1 & 0xffff0000u);              \
      float l2 = v[it].z - __uint_as_float(u2 & 0xffff0000u);              \
      float l3 = v[it].w - __uint_as_float(u3 & 0xffff0000u);              \
      uint2 hp, lp;                                                        \
      hp.x = (u0 >> 16) | (u1 & 0xffff0000u);                              \
      hp.y = (u2 >> 16) | (u3 & 0xffff0000u);                              \
      lp.x = (__float_as_uint(l0) >> 16) | (__float_as_uint(l1) & 0xffff0000u);\
      lp.y = (__float_as_uint(l2) >> 16) | (__float_as_uint(l3) & 0xffff0000u);\
      *(uint2*)((ADST) + rr * 64 + awoff) = hp;                            \
      *(uint2*)((ADST) + 8192 + rr * 64 + awoff) = lp;                     \
    }                                                                      \
  }

#define COMPUTE(AC, BC)                                                    \
  {                                                                        \
    _Pragma("unroll") for (int kh = 0; kh < 2; ++kh) {                     \
      int so = kh ? soff1 : soff0;                                         \
      bf16x8 ah[2], al[2], bh[2], bl[2];                                   \
      _Pragma("unroll") for (int mt = 0; mt < 2; ++mt) {                   \
        ah[mt] = *(bf16x8*)((AC) + rbA + mt * 2048 + so);                  \
        al[mt] = *(bf16x8*)((AC) + 8192 + rbA + mt * 2048 + so);           \
        bh[mt] = *(bf16x8*)((BC) + rbB + mt * 2048 + so);                  \
        bl[mt] = *(bf16x8*)((BC) + 8192 + rbB + mt * 2048 + so);           \
      }                                                                    \
      _Pragma("unroll") for (int mt = 0; mt < 2; ++mt)                     \
        _Pragma("unroll") for (int nt = 0; nt < 2; ++nt) {                 \
          acc[mt][nt] = __builtin_amdgcn_mfma_f32_32x32x16_bf16(           \
              ah[mt], bh[nt], acc[mt][nt], 0, 0, 0);                       \
          acc[mt][nt] = __builtin_amdgcn_mfma_f32_32x32x16_bf16(           \
              ah[mt], bl[nt], acc[mt][nt], 0, 0, 0);                       \
          acc[mt][nt] = __builtin_amdgcn_mfma_f32_32x32x16_bf16(           \
              al[mt], bh[nt], acc[mt][nt], 0, 0, 0);                       \
        }                                                                  \
    }                                                                      \
  }

  STAGE_ISSUE(0, B0)
  A_WRITE(A0)
  __syncthreads();

  for (int kc = 0; kc < 32; kc += 2) {
    STAGE_ISSUE(kc + 1, B1)
    COMPUTE(A0, B0)
    A_WRITE(A1)
    __syncthreads();
    if (kc + 2 < 32) { STAGE_ISSUE(kc + 2, B0) }
    COMPUTE(A1, B1)
    if (kc + 2 < 32) { A_WRITE(A0) }
    __syncthreads();
  }

#undef STAGE_ISSUE
#undef A_WRITE
#undef COMPUTE

  // --- epilogue part 1: score[row] += sum_o tanh(pre + bias[o]) * key[o]
  int col = lane & 31;
  int rbase = (lane >> 5) * 4;
  float bo[2], ko[2];
#pragma unroll
  for (int nt = 0; nt < 2; ++nt) {
    int o = ct * 128 + wn * 64 + nt * 32 + col;
    bo[nt] = bias[o];
    ko[nt] = key[o];
  }
  float* srow = scores + (size_t)b * SS + s0;
#pragma unroll
  for (int mt = 0; mt < 2; ++mt) {
#pragma unroll
    for (int reg = 0; reg < 16; ++reg) {
      float sv = tanhf(acc[mt][0][reg] + bo[0]) * ko[0] +
                 tanhf(acc[mt][1][reg] + bo[1]) * ko[1];
#pragma unroll
      for (int off = 1; off < 32; off <<= 1) sv += __shfl_xor(sv, off);
      if (col == 0) {
        int row = wm * 64 + mt * 32 + (reg & 3) + 8 * (reg >> 2) + rbase;
        atomicAdd(srow + row, sv);
      }
    }
  }

  if (!fused) return;

  // --- epilogue part 2: arrival barrier; last block does tile softmax+wsum --
  __threadfence();                    // release: score adds visible device-wide
  __syncthreads();
  float* fl = (float*)lds;            // K-loop done; reuse LDS
  float* sc_l = fl;                   // [128] tile scores
  float* e_l = fl + 128;              // [128] exp weights
  float* red = fl + 256;              // [8] reduce scratch
  int* flagI = (int*)(fl + 280);
  if (tid == 0) flagI[0] = (atomicAdd(&cnt[t], 1) == 7) ? 1 : 0;
  __syncthreads();
  if (!flagI[0]) return;

  int L = lengths[b];
  int rv = min(128, L - s0);          // >= 1 (s0 < L guaranteed)

  // coherent read-back of the completed scores (atomic read bypasses L1)
  if (tid < 128) {
    float s = (tid < rv) ? atomicAdd(&srow[tid], 0.0f) : 0.f;
    sc_l[tid] = s;
  }
  __syncthreads();

  // m_t = max over valid rows (threads 0..127 = 2 waves)
  if (tid < 128) {
    float mv = (tid < rv) ? sc_l[tid] : -3.0e38f;
#pragma unroll
    for (int off = 32; off > 0; off >>= 1) mv = fmaxf(mv, __shfl_xor(mv, off));
    if ((tid & 63) == 0) red[tid >> 6] = mv;
  }
  __syncthreads();
  float m_t = fmaxf(red[0], red[1]);

  // e_r = exp(sc - m_t), z_t = sum e_r
  if (tid < 128) {
    float e = (tid < rv) ? expf(sc_l[tid] - m_t) : 0.f;
    e_l[tid] = e;
#pragma unroll
    for (int off = 32; off > 0; off >>= 1) e += __shfl_xor(e, off);
    if ((tid & 63) == 0) red[2 + (tid >> 6)] = e;
  }
  __syncthreads();
  float z_t = red[2] + red[3];

  // v_t[h] = sum_r e_r * x[r,h]  (x tile is L2-hot; 8-deep batched loads)
  int h4 = tid << 2;
  float4 a4 = {0.f, 0.f, 0.f, 0.f};
  int r = 0;
  for (; r + 8 <= rv; r += 8) {
    float4 xv[8];
#pragma unroll
    for (int jj = 0; jj < 8; ++jj)
      xv[jj] = *(const float4*)(xb + (size_t)(r + jj) * HH + h4);
#pragma unroll
    for (int jj = 0; jj < 8; ++jj) {
      float ww = e_l[r + jj];
      a4.x = fmaf(ww, xv[jj].x, a4.x);
      a4.y = fmaf(ww, xv[jj].y, a4.y);
      a4.z = fmaf(ww, xv[jj].z, a4.z);
      a4.w = fmaf(ww, xv[jj].w, a4.w);
    }
  }
  for (; r < rv; ++r) {
    float ww = e_l[r];
    float4 xv = *(const float4*)(xb + (size_t)r * HH + h4);
    a4.x = fmaf(ww, xv.x, a4.x);
    a4.y = fmaf(ww, xv.y, a4.y);
    a4.z = fmaf(ww, xv.z, a4.z);
    a4.w = fmaf(ww, xv.w, a4.w);
  }
  *(float4*)(vb + (size_t)t * HH + h4) = a4;
  if (tid == 0) { mzb[2 * t] = m_t; mzb[2 * t + 1] = z_t; }
}

// ---- combine: out[b][h] = (1/Z) * sum_t exp(m_t - M) * v_t[h] --------------
__global__ __launch_bounds__(256) void combine_kernel(
    const float* __restrict__ mzb, const float* __restrict__ vb,
    const int* __restrict__ lengths, float* __restrict__ out) {
  int b = blockIdx.x;
  int L = lengths[b];
  int nt = (L + 127) >> 7;            // valid tiles, 1..32
  float M = -3.0e38f;
  for (int tt = 0; tt < nt; ++tt) M = fmaxf(M, mzb[2 * (b * 32 + tt)]);
  float Z = 0.f;
  for (int tt = 0; tt < nt; ++tt)
    Z += mzb[2 * (b * 32 + tt) + 1] * expf(mzb[2 * (b * 32 + tt)] - M);
  float inv = 1.f / Z;
  int h4 = threadIdx.x << 2;
  float4 a4 = {0.f, 0.f, 0.f, 0.f};
  for (int tt = 0; tt < nt; ++tt) {
    float wv = expf(mzb[2 * (b * 32 + tt)] - M) * inv;
    float4 v4 = *(const float4*)(vb + (size_t)(b * 32 + tt) * HH + h4);
    a4.x = fmaf(wv, v4.x, a4.x);
    a4.y = fmaf(wv, v4.y, a4.y);
    a4.z = fmaf(wv, v4.z, a4.z);
    a4.w = fmaf(wv, v4.w, a4.w);
  }
  *(float4*)(out + (size_t)b * HH + h4) = a4;
}

// ================= fallback path (round-3 kernels, verbatim) =================
__global__ __launch_bounds__(1024) void softmax_kernel(float* __restrict__ sc,
                                                       const int* __restrict__ lengths) {
  int b = blockIdx.x;
  int L = lengths[b];
  float* p = sc + (size_t)b * SS;
  __shared__ float sred[18];
  int tid = threadIdx.x;

  float m = -3.0e38f;
  for (int s = tid; s < L; s += 1024) m = fmaxf(m, p[s]);
  for (int off = 32; off > 0; off >>= 1) m = fmaxf(m, __shfl_down(m, off));
  if ((tid & 63) == 0) sred[tid >> 6] = m;
  __syncthreads();
  if (tid == 0) {
    float mm = sred[0];
    for (int w = 1; w < 16; ++w) mm = fmaxf(mm, sred[w]);
    sred[16] = mm;
  }
  __syncthreads();
  m = sred[16];

  float z = 0.f;
  for (int s = tid; s < L; s += 1024) {
    float e = expf(p[s] - m);
    p[s] = e;
    z += e;
  }
  for (int off = 32; off > 0; off >>= 1) z += __shfl_down(z, off);
  if ((tid & 63) == 0) sred[tid >> 6] = z;
  __syncthreads();
  if (tid == 0) {
    float zz = 0.f;
    for (int w = 0; w < 16; ++w) zz += sred[w];
    sred[17] = zz;
  }
  __syncthreads();
  float inv = 1.f / sred[17];
  for (int s = tid; s < L; s += 1024) p[s] *= inv;
}

__global__ __launch_bounds__(256) void wsum_partial(const float* __restrict__ x,
                                                    const float* __restrict__ p,
                                                    const int* __restrict__ lengths,
                                                    float* __restrict__ part) {
  int b = blockIdx.y;
  int L = lengths[b];
  int c = blockIdx.x;
  int sbeg = c * SCH;
  if (sbeg >= L) return;
  int send = min(sbeg + SCH, L);
  int h = threadIdx.x * 4;
  const float* xb = x + (size_t)b * SS * HH + h;
  const float* pb = p + (size_t)b * SS;
  float4 acc = {0.f, 0.f, 0.f, 0.f};
  int s = sbeg;
  for (; s + 8 <= send; s += 8) {
    float4 pa = *(const float4*)(pb + s);
    float4 pc = *(const float4*)(pb + s + 4);
    float4 vv[8];
#pragma unroll
    for (int jj = 0; jj < 8; ++jj)
      vv[jj] = *(const float4*)(xb + (size_t)(s + jj) * HH);
    float pw[8] = {pa.x, pa.y, pa.z, pa.w, pc.x, pc.y, pc.z, pc.w};
#pragma unroll
    for (int jj = 0; jj < 8; ++jj) {
      acc.x = fmaf(pw[jj], vv[jj].x, acc.x);
      acc.y = fmaf(pw[jj], vv[jj].y, acc.y);
      acc.z = fmaf(pw[jj], vv[jj].z, acc.z);
      acc.w = fmaf(pw[jj], vv[jj].w, acc.w);
    }
  }
  for (; s < send; ++s) {
    float wgt = pb[s];
    float4 vx = *(const float4*)(xb + (size_t)s * HH);
    acc.x = fmaf(wgt, vx.x, acc.x);
    acc.y = fmaf(wgt, vx.y, acc.y);
    acc.z = fmaf(wgt, vx.z, acc.z);
    acc.w = fmaf(wgt, vx.w, acc.w);
  }
  *(float4*)(part + ((size_t)b * (SS / SCH) + c) * HH + h) = acc;
}

__global__ __launch_bounds__(256) void wsum_reduce(const float* __restrict__ part,
                                                   const int* __restrict__ lengths,
                                                   float* __restrict__ out) {
  int b = blockIdx.x;
  int nc = (lengths[b] + SCH - 1) / SCH;
  int h = threadIdx.x * 4;
  const float* pb = part + (size_t)b * (SS / SCH) * HH + h;
  float4 acc = {0.f, 0.f, 0.f, 0.f};
  int c = 0;
  for (; c + 8 <= nc; c += 8) {
    float4 v[8];
#pragma unroll
    for (int jj = 0; jj < 8; ++jj) v[jj] = *(const float4*)(pb + (size_t)(c + jj) * HH);
#pragma unroll
    for (int jj = 0; jj < 8; ++jj) {
      acc.x += v[jj].x; acc.y += v[jj].y; acc.z += v[jj].z; acc.w += v[jj].w;
    }
  }
  for (; c < nc; ++c) {
    float4 v = *(const float4*)(pb + (size_t)c * HH);
    acc.x += v.x; acc.y += v.y; acc.z += v.z; acc.w += v.w;
  }
  *(float4*)(out + (size_t)b * HH + h) = acc;
}

extern "C" void kernel_launch(void* const* d_in, const int* in_sizes, int n_in,
                              void* d_out, int out_size, void* d_ws, size_t ws_size,
                              hipStream_t stream) {
  const float* x = (const float*)d_in[0];
  const int* lengths = (const int*)d_in[1];
  const float* W = (const float*)d_in[2];
  const float* bias = (const float*)d_in[3];
  const float* key = (const float*)d_in[4];
  float* out = (float*)d_out;

  char* ws = (char*)d_ws;
  unsigned short* Bbuf = (unsigned short*)ws;                       // 4 MB
  float* scores = (float*)(ws + (size_t)4 * 1024 * 1024);           // 256 KB
  int* cnt = (int*)(ws + (size_t)4 * 1024 * 1024 + 256 * 1024);     // 2 KB
  float* mzb = (float*)(ws + (size_t)4 * 1024 * 1024 + 258 * 1024); // 4 KB
  float* vbuf = (float*)(ws + (size_t)4 * 1024 * 1024 + 272 * 1024);// 2 MB
  const size_t NEED = (size_t)4 * 1024 * 1024 + 272 * 1024 + (size_t)2 * 1024 * 1024;

  if (ws_size >= NEED) {
    // fused path: scores + counters zeroed together (258 KB)
    hipMemsetAsync(scores, 0, 258 * 1024, stream);
    conv_w<<<dim3(8, 32), 256, 0, stream>>>(W, Bbuf);
    scores_gemm<<<dim3(8, 512), 256, 0, stream>>>(x, lengths, Bbuf, bias, key,
                                                  scores, cnt, mzb, vbuf, 1);
    combine_kernel<<<dim3(BB), 256, 0, stream>>>(mzb, vbuf, lengths, out);
  } else {
    // fallback: round-3 path (part aliases Bbuf after gemm)
    float* part = (float*)ws;
    hipMemsetAsync(scores, 0, (size_t)BB * SS * sizeof(float), stream);
    conv_w<<<dim3(8, 32), 256, 0, stream>>>(W, Bbuf);
    scores_gemm<<<dim3(8, 512), 256, 0, stream>>>(x, lengths, Bbuf, bias, key,
                                                  scores, (int*)nullptr,
                                                  (float*)nullptr, (float*)nullptr, 0);
    softmax_kernel<<<dim3(BB), 1024, 0, stream>>>(scores, lengths);
    wsum_partial<<<dim3(SS / SCH, BB), 256, 0, stream>>>(x, scores, lengths, part);
    wsum_reduce<<<dim3(BB), 256, 0, stream>>>(part, lengths, out);
  }
}